// Round 2
// baseline (319.173 us; speedup 1.0000x reference)
//
#include <hip/hip_runtime.h>
#include <stdint.h>

// Problem constants (fixed by setup_inputs in the reference)
#define BATCH 32
#define HDIM  1024
#define WDIM  1024
#define H2    (HDIM / 2)
#define W2    (WDIM / 2)
#define NSTN  256                 // stations per batch
#define NBLOCKS 2048              // 8 blocks/CU * 256 CU, fully resident
#define NTHREADS (NBLOCKS * 256)  // 524288

// ---------------------------------------------------------------------------
// Wave-64 + LDS block reduction (sum). Block size = 256.
// ---------------------------------------------------------------------------
__device__ __forceinline__ float blockReduceSum(float v, float* smem) {
    #pragma unroll
    for (int off = 32; off > 0; off >>= 1)
        v += __shfl_down(v, off, 64);
    const int lane = threadIdx.x & 63;
    const int wid  = threadIdx.x >> 6;
    if (lane == 0) smem[wid] = v;
    __syncthreads();
    v = (threadIdx.x < 4) ? smem[threadIdx.x] : 0.0f;
    if (wid == 0) {
        v += __shfl_down(v, 2, 64);
        v += __shfl_down(v, 1, 64);
    }
    return v;
}

// ---------------------------------------------------------------------------
// Fused kernel: image MSE (bilinear 2x upsampled target) + station box-mean
// MSE + last-block finalize.
//
// jax.image.resize 'bilinear' 512->1024 (half-pixel centers):
//   even row y=2m:  0.25*t[m-1] + 0.75*t[m]   (index-clamped == edge renorm)
//   odd  row y=2m+1: 0.75*t[m] + 0.25*t[m+1]
// Each thread processes a 4(x) x 2(y) pixel tile: 2 float4 pred loads,
// 12 scalar target loads (3 rows x 4 cols) -> 8 output pixels.
//
// acc layout in d_ws: acc[0]=img sum, acc[1]=stn sum, acc[2]=block counter.
// ---------------------------------------------------------------------------
__global__ __launch_bounds__(256) void fused_loss_kernel(
        const float* __restrict__ pred,
        const float* __restrict__ tgt,
        const int*   __restrict__ pos,
        const float* __restrict__ runoff,
        float* __restrict__ acc,
        float* __restrict__ out) {
    __shared__ float smem[4];

    // ---- station loss (blocks 0..31, one thread per station) ----
    float stn_local = 0.0f;
    if (blockIdx.x < 32) {
        const int idx = blockIdx.x * 256 + threadIdx.x;   // 32*256 = 8192 = B*S
        const int b  = idx >> 8;                          // NSTN = 256
        const int px = pos[idx * 2 + 0];
        const int py = pos[idx * 2 + 1];
        const float* p = pred + (int64_t)b * HDIM * WDIM;
        float sum = 0.0f; int cnt = 0;
        #pragma unroll
        for (int dy = -1; dy <= 1; ++dy) {
            const int y = py + dy;
            if (y < 0 || y >= HDIM) continue;
            #pragma unroll
            for (int dx = -1; dx <= 1; ++dx) {
                const int x = px + dx;
                if (x < 0 || x >= WDIM) continue;
                sum += p[y * WDIM + x];
                cnt++;
            }
        }
        const float d = sum / (float)cnt - runoff[idx];
        stn_local = d * d;
    }

    // ---- image loss: grid-stride over 4x2 tiles ----
    // units: b(32) * ypair(512) * xgroup(256) = 4,194,304 ; 8 per thread
    float img_local = 0.0f;
    const int total_units = BATCH * (HDIM / 2) * (WDIM / 4);
    for (int u = blockIdx.x * 256 + threadIdx.x; u < total_units; u += NTHREADS) {
        const int xg = u & 255;           // WDIM/4 = 256
        const int yp = (u >> 8) & 511;    // HDIM/2 = 512
        const int b  = u >> 17;
        const int x0 = xg << 2;
        const int m0 = xg << 1;           // x0/2, even

        const float* prow = pred + (((int64_t)b * HDIM + (yp << 1)) << 10) + x0;
        const float4 pe = *(const float4*)(prow);         // even row 2*yp
        const float4 po = *(const float4*)(prow + WDIM);  // odd  row 2*yp+1

        const int ym1 = (yp == 0)      ? 0      : yp - 1;
        const int yp1 = (yp == H2 - 1) ? H2 - 1 : yp + 1;
        const int xm1 = (m0 == 0)      ? 0      : m0 - 1;
        const int xp2 = (m0 + 2 >= W2) ? W2 - 1 : m0 + 2;

        const float* tm1 = tgt + (((int64_t)b * H2 + ym1) << 9);
        const float* t0  = tgt + (((int64_t)b * H2 + yp ) << 9);
        const float* tp1 = tgt + (((int64_t)b * H2 + yp1) << 9);

        const float am1 = tm1[xm1], a0 = tm1[m0], a1 = tm1[m0 + 1], a2 = tm1[xp2];
        const float bm1 = t0 [xm1], b0 = t0 [m0], b1 = t0 [m0 + 1], b2 = t0 [xp2];
        const float cm1 = tp1[xm1], c0 = tp1[m0], c1 = tp1[m0 + 1], c2 = tp1[xp2];

        // vertical interp for even output row (2*yp): 0.25*t[m-1] + 0.75*t[m]
        const float e_m1 = 0.25f * am1 + 0.75f * bm1;
        const float e_0  = 0.25f * a0  + 0.75f * b0;
        const float e_1  = 0.25f * a1  + 0.75f * b1;
        const float e_2  = 0.25f * a2  + 0.75f * b2;
        // vertical interp for odd output row (2*yp+1): 0.75*t[m] + 0.25*t[m+1]
        const float o_m1 = 0.75f * bm1 + 0.25f * cm1;
        const float o_0  = 0.75f * b0  + 0.25f * c0;
        const float o_1  = 0.75f * b1  + 0.25f * c1;
        const float o_2  = 0.75f * b2  + 0.25f * c2;

        // horizontal interp (even,odd,even,odd in x) + squared diff
        float d0 = pe.x - (0.25f * e_m1 + 0.75f * e_0);
        float d1 = pe.y - (0.75f * e_0  + 0.25f * e_1);
        float d2 = pe.z - (0.25f * e_0  + 0.75f * e_1);
        float d3 = pe.w - (0.75f * e_1  + 0.25f * e_2);
        img_local += d0 * d0 + d1 * d1 + d2 * d2 + d3 * d3;

        d0 = po.x - (0.25f * o_m1 + 0.75f * o_0);
        d1 = po.y - (0.75f * o_0  + 0.25f * o_1);
        d2 = po.z - (0.25f * o_0  + 0.75f * o_1);
        d3 = po.w - (0.75f * o_1  + 0.25f * o_2);
        img_local += d0 * d0 + d1 * d1 + d2 * d2 + d3 * d3;
    }

    // ---- reductions + atomics ----
    const float bi = blockReduceSum(img_local, smem);
    if (threadIdx.x == 0) atomicAdd(&acc[0], bi);
    if (blockIdx.x < 32) {
        __syncthreads();   // smem reuse hazard between the two reductions
        const float bs = blockReduceSum(stn_local, smem);
        if (threadIdx.x == 0) atomicAdd(&acc[1], bs);
    }

    // ---- last-block finalize (device-scope atomics; XCD-safe) ----
    if (threadIdx.x == 0) {
        __threadfence();   // release: our acc atomics visible before counter bump
        const unsigned old = atomicAdd((unsigned*)&acc[2], 1u);
        if (old == NBLOCKS - 1) {
            __threadfence();   // acquire
            // atomic RMW reads -> coherent across XCDs
            const float is = atomicAdd(&acc[0], 0.0f);
            const float ss = atomicAdd(&acc[1], 0.0f);
            const float img = is * (1.0f / ((float)BATCH * HDIM * WDIM));
            const float stn = ss * (1.0f / ((float)BATCH * NSTN));
            out[0] = img + 0.5f * stn;   // IMAGE_W=1.0, STATION_W=0.5
            out[1] = img;
            out[2] = stn;
        }
    }
}

extern "C" void kernel_launch(void* const* d_in, const int* in_sizes, int n_in,
                              void* d_out, int out_size, void* d_ws, size_t ws_size,
                              hipStream_t stream) {
    const float* pred   = (const float*)d_in[0];
    const float* tgt    = (const float*)d_in[1];
    const int*   pos    = (const int*)d_in[2];
    const float* runoff = (const float*)d_in[3];
    float* out = (float*)d_out;
    float* acc = (float*)d_ws;   // [0]=img sum, [1]=stn sum, [2]=counter

    hipMemsetAsync(acc, 0, 3 * sizeof(float), stream);
    fused_loss_kernel<<<NBLOCKS, 256, 0, stream>>>(pred, tgt, pos, runoff, acc, out);
}

// Round 3
// 221.087 us; speedup vs baseline: 1.4437x; 1.4437x over previous
//
#include <hip/hip_runtime.h>
#include <stdint.h>

// Problem constants (fixed by setup_inputs in the reference)
#define BATCH 32
#define HDIM  1024
#define WDIM  1024
#define H2    (HDIM / 2)
#define W2    (WDIM / 2)
#define NSTN  256                 // stations per batch
#define NBLOCKS 2048              // 8 blocks/CU * 256 CU, fully resident
#define NTHREADS (NBLOCKS * 256)  // 524288

// ---------------------------------------------------------------------------
// Wave-64 + LDS block reduction (sum). Block size = 256. Result in thread 0.
// Caller must __syncthreads() between successive uses (smem reuse).
// ---------------------------------------------------------------------------
__device__ __forceinline__ float blockReduceSum(float v, float* smem) {
    #pragma unroll
    for (int off = 32; off > 0; off >>= 1)
        v += __shfl_down(v, off, 64);
    const int lane = threadIdx.x & 63;
    const int wid  = threadIdx.x >> 6;
    if (lane == 0) smem[wid] = v;
    __syncthreads();
    v = (threadIdx.x < 4) ? smem[threadIdx.x] : 0.0f;
    if (wid == 0) {
        v += __shfl_down(v, 2, 64);
        v += __shfl_down(v, 1, 64);
    }
    return v;
}

// ---------------------------------------------------------------------------
// Kernel A: image MSE partials (all blocks) + station MSE partials (blocks
// 0..31). NO atomics, NO fences — each block stores its partial to a unique
// slot; kernel B reduces. This removes the 2x2048 same-address device-atomic
// + per-block __threadfence tail that made round 2 latency-bound (VALUBusy
// 5.7%, HBM 8.9%, occupancy 50%).
//
// jax.image.resize 'bilinear' 512->1024 (half-pixel centers):
//   even row y=2m:  0.25*t[m-1] + 0.75*t[m]   (index-clamped == edge renorm)
//   odd  row y=2m+1: 0.75*t[m] + 0.25*t[m+1]
// Each thread processes a 4(x) x 2(y) pixel tile: 2 float4 pred loads,
// 12 scalar target loads (L1/L2-resident, heavily reused within a block).
// ---------------------------------------------------------------------------
__global__ __launch_bounds__(256) void fused_compute_kernel(
        const float* __restrict__ pred,
        const float* __restrict__ tgt,
        const int*   __restrict__ pos,
        const float* __restrict__ runoff,
        float* __restrict__ img_part,    // [NBLOCKS]
        float* __restrict__ stn_part) {  // [32]
    __shared__ float smem[4];

    // ---- station partial (blocks 0..31, one thread per station) ----
    if (blockIdx.x < 32) {
        const int idx = blockIdx.x * 256 + threadIdx.x;   // 32*256 = B*S
        const int b  = idx >> 8;                          // NSTN = 256
        const int px = pos[idx * 2 + 0];
        const int py = pos[idx * 2 + 1];
        const float* p = pred + (int64_t)b * HDIM * WDIM;
        float sum = 0.0f; int cnt = 0;
        #pragma unroll
        for (int dy = -1; dy <= 1; ++dy) {
            const int y = py + dy;
            if (y < 0 || y >= HDIM) continue;
            #pragma unroll
            for (int dx = -1; dx <= 1; ++dx) {
                const int x = px + dx;
                if (x < 0 || x >= WDIM) continue;
                sum += p[y * WDIM + x];
                cnt++;
            }
        }
        const float d = sum / (float)cnt - runoff[idx];
        const float bs = blockReduceSum(d * d, smem);
        if (threadIdx.x == 0) stn_part[blockIdx.x] = bs;
        __syncthreads();   // smem reuse hazard before img reduction
    }

    // ---- image loss: grid-stride over 4x2 tiles ----
    // units: b(32) * ypair(512) * xgroup(256) = 4,194,304 ; 8 per thread
    float img_local = 0.0f;
    const int total_units = BATCH * (HDIM / 2) * (WDIM / 4);
    for (int u = blockIdx.x * 256 + threadIdx.x; u < total_units; u += NTHREADS) {
        const int xg = u & 255;           // WDIM/4 = 256
        const int yp = (u >> 8) & 511;    // HDIM/2 = 512
        const int b  = u >> 17;
        const int x0 = xg << 2;
        const int m0 = xg << 1;           // x0/2, even

        const float* prow = pred + (((int64_t)b * HDIM + (yp << 1)) << 10) + x0;
        const float4 pe = *(const float4*)(prow);         // even row 2*yp
        const float4 po = *(const float4*)(prow + WDIM);  // odd  row 2*yp+1

        const int ym1 = (yp == 0)      ? 0      : yp - 1;
        const int yp1 = (yp == H2 - 1) ? H2 - 1 : yp + 1;
        const int xm1 = (m0 == 0)      ? 0      : m0 - 1;
        const int xp2 = (m0 + 2 >= W2) ? W2 - 1 : m0 + 2;

        const float* tm1 = tgt + (((int64_t)b * H2 + ym1) << 9);
        const float* t0  = tgt + (((int64_t)b * H2 + yp ) << 9);
        const float* tp1 = tgt + (((int64_t)b * H2 + yp1) << 9);

        const float am1 = tm1[xm1], a0 = tm1[m0], a1 = tm1[m0 + 1], a2 = tm1[xp2];
        const float bm1 = t0 [xm1], b0 = t0 [m0], b1 = t0 [m0 + 1], b2 = t0 [xp2];
        const float cm1 = tp1[xm1], c0 = tp1[m0], c1 = tp1[m0 + 1], c2 = tp1[xp2];

        // vertical interp, even output row (2*yp): 0.25*t[m-1] + 0.75*t[m]
        const float e_m1 = 0.25f * am1 + 0.75f * bm1;
        const float e_0  = 0.25f * a0  + 0.75f * b0;
        const float e_1  = 0.25f * a1  + 0.75f * b1;
        const float e_2  = 0.25f * a2  + 0.75f * b2;
        // vertical interp, odd output row (2*yp+1): 0.75*t[m] + 0.25*t[m+1]
        const float o_m1 = 0.75f * bm1 + 0.25f * cm1;
        const float o_0  = 0.75f * b0  + 0.25f * c0;
        const float o_1  = 0.75f * b1  + 0.25f * c1;
        const float o_2  = 0.75f * b2  + 0.25f * c2;

        // horizontal interp (even,odd,even,odd in x) + squared diff
        float d0 = pe.x - (0.25f * e_m1 + 0.75f * e_0);
        float d1 = pe.y - (0.75f * e_0  + 0.25f * e_1);
        float d2 = pe.z - (0.25f * e_0  + 0.75f * e_1);
        float d3 = pe.w - (0.75f * e_1  + 0.25f * e_2);
        img_local += d0 * d0 + d1 * d1 + d2 * d2 + d3 * d3;

        d0 = po.x - (0.25f * o_m1 + 0.75f * o_0);
        d1 = po.y - (0.75f * o_0  + 0.25f * o_1);
        d2 = po.z - (0.25f * o_0  + 0.75f * o_1);
        d3 = po.w - (0.75f * o_1  + 0.25f * o_2);
        img_local += d0 * d0 + d1 * d1 + d2 * d2 + d3 * d3;
    }

    const float bi = blockReduceSum(img_local, smem);
    if (threadIdx.x == 0) img_part[blockIdx.x] = bi;
}

// ---------------------------------------------------------------------------
// Kernel B: reduce 2048 img partials + 32 stn partials, write 3 outputs.
// One block of 256 threads; coalesced partial reads; ~2 us.
// ---------------------------------------------------------------------------
__global__ __launch_bounds__(256) void finalize_kernel(
        const float* __restrict__ img_part,
        const float* __restrict__ stn_part,
        float* __restrict__ out) {
    __shared__ float smem[4];

    float v = 0.0f;
    #pragma unroll
    for (int i = 0; i < NBLOCKS / 256; ++i)
        v += img_part[threadIdx.x + i * 256];
    const float img_sum = blockReduceSum(v, smem);
    __syncthreads();   // smem reuse

    float s = (threadIdx.x < 32) ? stn_part[threadIdx.x] : 0.0f;
    const float stn_sum = blockReduceSum(s, smem);

    if (threadIdx.x == 0) {
        const float img = img_sum * (1.0f / ((float)BATCH * HDIM * WDIM));
        const float stn = stn_sum * (1.0f / ((float)BATCH * NSTN));
        out[0] = img + 0.5f * stn;   // IMAGE_W=1.0, STATION_W=0.5
        out[1] = img;
        out[2] = stn;
    }
}

extern "C" void kernel_launch(void* const* d_in, const int* in_sizes, int n_in,
                              void* d_out, int out_size, void* d_ws, size_t ws_size,
                              hipStream_t stream) {
    const float* pred   = (const float*)d_in[0];
    const float* tgt    = (const float*)d_in[1];
    const int*   pos    = (const int*)d_in[2];
    const float* runoff = (const float*)d_in[3];
    float* out = (float*)d_out;
    float* img_part = (float*)d_ws;            // [NBLOCKS]
    float* stn_part = img_part + NBLOCKS;      // [32]

    // No memset needed: every partial slot is written unconditionally.
    fused_compute_kernel<<<NBLOCKS, 256, 0, stream>>>(pred, tgt, pos, runoff,
                                                      img_part, stn_part);
    finalize_kernel<<<1, 256, 0, stream>>>(img_part, stn_part, out);
}

// Round 4
// 216.202 us; speedup vs baseline: 1.4763x; 1.0226x over previous
//
#include <hip/hip_runtime.h>
#include <stdint.h>

// Problem constants (fixed by setup_inputs in the reference)
#define BATCH 32
#define HDIM  1024
#define WDIM  1024
#define H2    (HDIM / 2)
#define W2    (WDIM / 2)
#define NSTN  256                 // stations per batch
#define NBLOCKS 2048              // 8 blocks/CU * 256 CU, fully resident
#define NTHREADS (NBLOCKS * 256)  // 524288

// ---------------------------------------------------------------------------
// Wave-64 + LDS block reduction (sum). Block size = 256. Result in thread 0.
// Caller must __syncthreads() between successive uses (smem reuse).
// ---------------------------------------------------------------------------
__device__ __forceinline__ float blockReduceSum(float v, float* smem) {
    #pragma unroll
    for (int off = 32; off > 0; off >>= 1)
        v += __shfl_down(v, off, 64);
    const int lane = threadIdx.x & 63;
    const int wid  = threadIdx.x >> 6;
    if (lane == 0) smem[wid] = v;
    __syncthreads();
    v = (threadIdx.x < 4) ? smem[threadIdx.x] : 0.0f;
    if (wid == 0) {
        v += __shfl_down(v, 2, 64);
        v += __shfl_down(v, 1, 64);
    }
    return v;
}

// ---------------------------------------------------------------------------
// Kernel A: image MSE partials (all blocks) + station MSE partials (blocks
// 0..31). Partials to unique slots (no atomics/fences — round 2 lesson).
//
// Image loss, 8(x) x 2(y) tile per thread per iteration:
//   4 float4 pred loads + 3 float4 tgt loads (rows yp-1, yp, yp+1, cols
//   m0..m0+3). Edge cols m0-1 / m0+4 come from __shfl_up/__shfl_down of the
//   neighbor lane's float4 (consecutive lanes = consecutive col-groups within
//   a wave by construction), with exec-masked scalar loads only in lanes
//   0/63 (covers both the wave boundary and the global clamp). This cuts
//   VMEM instructions 4x vs the round-3 12-scalar-load version (the
//   VMEM-issue bottleneck: 1.75 -> 0.44 instr/pixel).
//
// jax.image.resize 'bilinear' 512->1024 (half-pixel centers):
//   even y=2m:  0.25*t[m-1] + 0.75*t[m]   (index-clamped == edge renorm)
//   odd  y=2m+1: 0.75*t[m] + 0.25*t[m+1]  (same in x)
// ---------------------------------------------------------------------------
__global__ __launch_bounds__(256) void fused_compute_kernel(
        const float* __restrict__ pred,
        const float* __restrict__ tgt,
        const int*   __restrict__ pos,
        const float* __restrict__ runoff,
        float* __restrict__ img_part,    // [NBLOCKS]
        float* __restrict__ stn_part) {  // [32]
    __shared__ float smem[4];
    const int lane = threadIdx.x & 63;

    // ---- station partial (blocks 0..31, one thread per station) ----
    if (blockIdx.x < 32) {
        const int idx = blockIdx.x * 256 + threadIdx.x;   // 32*256 = B*S
        const int b  = idx >> 8;                          // NSTN = 256
        const int px = pos[idx * 2 + 0];
        const int py = pos[idx * 2 + 1];
        const float* p = pred + (int64_t)b * HDIM * WDIM;
        float sum = 0.0f; int cnt = 0;
        #pragma unroll
        for (int dy = -1; dy <= 1; ++dy) {
            const int y = py + dy;
            if (y < 0 || y >= HDIM) continue;
            #pragma unroll
            for (int dx = -1; dx <= 1; ++dx) {
                const int x = px + dx;
                if (x < 0 || x >= WDIM) continue;
                sum += p[y * WDIM + x];
                cnt++;
            }
        }
        const float d = sum / (float)cnt - runoff[idx];
        const float bs = blockReduceSum(d * d, smem);
        if (threadIdx.x == 0) stn_part[blockIdx.x] = bs;
        __syncthreads();   // smem reuse hazard before img reduction
    }

    // ---- image loss: grid-stride over 8x2 tiles ----
    // units: b(32) * ypair(512) * xgroup8(128) = 2,097,152 ; exactly 4/thread
    float img_local = 0.0f;
    const int total_units = BATCH * (HDIM / 2) * (WDIM / 8);
    for (int u = blockIdx.x * 256 + threadIdx.x; u < total_units; u += NTHREADS) {
        const int xg = u & 127;           // WDIM/8 = 128 (wave: contiguous)
        const int yp = (u >> 7) & 511;    // HDIM/2 = 512 (uniform per wave)
        const int b  = u >> 16;
        const int x0 = xg << 3;
        const int m0 = xg << 2;

        const float* prow = pred + (((int64_t)b * HDIM + (yp << 1)) << 10) + x0;
        const float4 pe0 = ((const float4*)prow)[0];          // row 2yp
        const float4 pe1 = ((const float4*)prow)[1];
        const float4 po0 = ((const float4*)(prow + WDIM))[0]; // row 2yp+1
        const float4 po1 = ((const float4*)(prow + WDIM))[1];

        const int ym1 = (yp == 0)      ? 0      : yp - 1;
        const int yp1 = (yp == H2 - 1) ? H2 - 1 : yp + 1;
        const float* tA = tgt + (((int64_t)b * H2 + ym1) << 9);
        const float* tB = tgt + (((int64_t)b * H2 + yp ) << 9);
        const float* tC = tgt + (((int64_t)b * H2 + yp1) << 9);

        const float4 a4 = *(const float4*)(tA + m0);
        const float4 b4 = *(const float4*)(tB + m0);
        const float4 c4 = *(const float4*)(tC + m0);

        // neighbor columns via cross-lane; lanes 0/63 patch via scalar load
        float la = __shfl_up(a4.w, 1, 64);
        float lb = __shfl_up(b4.w, 1, 64);
        float lc = __shfl_up(c4.w, 1, 64);
        float ra = __shfl_down(a4.x, 1, 64);
        float rb = __shfl_down(b4.x, 1, 64);
        float rc = __shfl_down(c4.x, 1, 64);
        if (lane == 0) {
            const int xm1 = (m0 == 0) ? 0 : m0 - 1;
            la = tA[xm1]; lb = tB[xm1]; lc = tC[xm1];
        }
        if (lane == 63) {
            const int xp4 = (m0 + 4 > W2 - 1) ? W2 - 1 : m0 + 4;
            ra = tA[xp4]; rb = tB[xp4]; rc = tC[xp4];
        }

        // vertical interp across the 6-column window [m0-1 .. m0+4]
        float e[6], o[6];
        e[0] = 0.25f * la   + 0.75f * lb;    o[0] = 0.75f * lb   + 0.25f * lc;
        e[1] = 0.25f * a4.x + 0.75f * b4.x;  o[1] = 0.75f * b4.x + 0.25f * c4.x;
        e[2] = 0.25f * a4.y + 0.75f * b4.y;  o[2] = 0.75f * b4.y + 0.25f * c4.y;
        e[3] = 0.25f * a4.z + 0.75f * b4.z;  o[3] = 0.75f * b4.z + 0.25f * c4.z;
        e[4] = 0.25f * a4.w + 0.75f * b4.w;  o[4] = 0.75f * b4.w + 0.25f * c4.w;
        e[5] = 0.25f * ra   + 0.75f * rb;    o[5] = 0.75f * rb   + 0.25f * rc;

        const float pev[8] = {pe0.x, pe0.y, pe0.z, pe0.w, pe1.x, pe1.y, pe1.z, pe1.w};
        const float pov[8] = {po0.x, po0.y, po0.z, po0.w, po1.x, po1.y, po1.z, po1.w};

        // horizontal interp (even,odd pairs) + squared diff, 16 pixels
        #pragma unroll
        for (int k = 0; k < 4; ++k) {
            const float te0 = 0.25f * e[k]     + 0.75f * e[k + 1];
            const float te1 = 0.75f * e[k + 1] + 0.25f * e[k + 2];
            const float to0 = 0.25f * o[k]     + 0.75f * o[k + 1];
            const float to1 = 0.75f * o[k + 1] + 0.25f * o[k + 2];
            const float d0 = pev[2 * k]     - te0;
            const float d1 = pev[2 * k + 1] - te1;
            const float d2 = pov[2 * k]     - to0;
            const float d3 = pov[2 * k + 1] - to1;
            img_local += d0 * d0 + d1 * d1 + d2 * d2 + d3 * d3;
        }
    }

    const float bi = blockReduceSum(img_local, smem);
    if (threadIdx.x == 0) img_part[blockIdx.x] = bi;
}

// ---------------------------------------------------------------------------
// Kernel B: reduce 2048 img partials + 32 stn partials, write 3 outputs.
// ---------------------------------------------------------------------------
__global__ __launch_bounds__(256) void finalize_kernel(
        const float* __restrict__ img_part,
        const float* __restrict__ stn_part,
        float* __restrict__ out) {
    __shared__ float smem[4];

    float v = 0.0f;
    #pragma unroll
    for (int i = 0; i < NBLOCKS / 256; ++i)
        v += img_part[threadIdx.x + i * 256];
    const float img_sum = blockReduceSum(v, smem);
    __syncthreads();   // smem reuse

    float s = (threadIdx.x < 32) ? stn_part[threadIdx.x] : 0.0f;
    const float stn_sum = blockReduceSum(s, smem);

    if (threadIdx.x == 0) {
        const float img = img_sum * (1.0f / ((float)BATCH * HDIM * WDIM));
        const float stn = stn_sum * (1.0f / ((float)BATCH * NSTN));
        out[0] = img + 0.5f * stn;   // IMAGE_W=1.0, STATION_W=0.5
        out[1] = img;
        out[2] = stn;
    }
}

extern "C" void kernel_launch(void* const* d_in, const int* in_sizes, int n_in,
                              void* d_out, int out_size, void* d_ws, size_t ws_size,
                              hipStream_t stream) {
    const float* pred   = (const float*)d_in[0];
    const float* tgt    = (const float*)d_in[1];
    const int*   pos    = (const int*)d_in[2];
    const float* runoff = (const float*)d_in[3];
    float* out = (float*)d_out;
    float* img_part = (float*)d_ws;            // [NBLOCKS]
    float* stn_part = img_part + NBLOCKS;      // [32]

    // No memset needed: every partial slot is written unconditionally.
    fused_compute_kernel<<<NBLOCKS, 256, 0, stream>>>(pred, tgt, pos, runoff,
                                                      img_part, stn_part);
    finalize_kernel<<<1, 256, 0, stream>>>(img_part, stn_part, out);
}

// Round 5
// 214.717 us; speedup vs baseline: 1.4865x; 1.0069x over previous
//
#include <hip/hip_runtime.h>
#include <stdint.h>

// Problem constants (fixed by setup_inputs in the reference)
#define BATCH 32
#define HDIM  1024
#define WDIM  1024
#define H2    (HDIM / 2)
#define W2    (WDIM / 2)
#define NSTN  256                 // stations per batch
#define NBLOCKS 2048              // 8 blocks/CU * 256 CU, fully resident
#define NTHREADS (NBLOCKS * 256)  // 524288

// ---------------------------------------------------------------------------
// Wave-64 + LDS block reduction (sum). Block size = 256. Result in thread 0.
// ---------------------------------------------------------------------------
__device__ __forceinline__ float blockReduceSum(float v, float* smem) {
    #pragma unroll
    for (int off = 32; off > 0; off >>= 1)
        v += __shfl_down(v, off, 64);
    const int lane = threadIdx.x & 63;
    const int wid  = threadIdx.x >> 6;
    if (lane == 0) smem[wid] = v;
    __syncthreads();
    v = (threadIdx.x < 4) ? smem[threadIdx.x] : 0.0f;
    if (wid == 0) {
        v += __shfl_down(v, 2, 64);
        v += __shfl_down(v, 1, 64);
    }
    return v;
}

// ---------------------------------------------------------------------------
// Kernel A: image MSE partials (all blocks) + station MSE partials (blocks
// 0..31). Partials to unique d_ws slots (no atomics/fences — round-2 lesson).
//
// Image loss: unit u = b*65536 + yp*128 + xg (xg: 8-px group, yp: row pair).
// Grid stride NTHREADS = 8*65536, so a thread's 4 iterations share (yp, xg)
// and differ only in b — all row indices, clamps, and x-offsets are hoisted;
// the unrolled iterations are fully independent (52 VMEM loads schedulable
// up-front; intra-thread latency hiding).
//
// Per 8x2-px tile: 4 pred float4 + per tgt row (3 rows): 1 aligned float4 @
// m0 + 2 clamped scalar edge loads. 13 VMEM / 16 px, ZERO shuffles, ZERO
// divergent patch branches (round-4 lesson: ds_bpermute + lane-0/63 exec
// masking ate the entire VMEM saving).
//
// jax.image.resize 'bilinear' 512->1024 (half-pixel centers):
//   even y=2m:  0.25*t[m-1] + 0.75*t[m]   (index-clamped == edge renorm)
//   odd  y=2m+1: 0.75*t[m] + 0.25*t[m+1]  (same in x)
// ---------------------------------------------------------------------------
__global__ __launch_bounds__(256) void fused_compute_kernel(
        const float* __restrict__ pred,
        const float* __restrict__ tgt,
        const int*   __restrict__ pos,
        const float* __restrict__ runoff,
        float* __restrict__ img_part,    // [NBLOCKS]
        float* __restrict__ stn_part) {  // [32]
    __shared__ float smem[4];

    // ---- station partial (blocks 0..31, one thread per station) ----
    if (blockIdx.x < 32) {
        const int idx = blockIdx.x * 256 + threadIdx.x;   // 32*256 = B*S
        const int bb = idx >> 8;                          // NSTN = 256
        const int px = pos[idx * 2 + 0];
        const int py = pos[idx * 2 + 1];
        const float* p = pred + ((int64_t)bb << 20);
        float sum = 0.0f; int cnt = 0;
        #pragma unroll
        for (int dy = -1; dy <= 1; ++dy) {
            const int y = py + dy;
            if (y < 0 || y >= HDIM) continue;
            #pragma unroll
            for (int dx = -1; dx <= 1; ++dx) {
                const int x = px + dx;
                if (x < 0 || x >= WDIM) continue;
                sum += p[y * WDIM + x];
                cnt++;
            }
        }
        const float d = sum / (float)cnt - runoff[idx];
        const float bs = blockReduceSum(d * d, smem);
        if (threadIdx.x == 0) stn_part[blockIdx.x] = bs;
        __syncthreads();   // smem reuse hazard before img reduction
    }

    // ---- image loss: 4 independent b-iterations, hoisted geometry ----
    const int tid = blockIdx.x * 256 + threadIdx.x;
    const int xg = tid & 127;            // 8-px x-group (wave: contiguous)
    const int yp = (tid >> 7) & 511;     // row pair
    const int b0 = tid >> 16;            // 0..7
    const int x0 = xg << 3;
    const int m0 = xg << 2;

    const int ym1 = (yp == 0)      ? 0      : yp - 1;
    const int yp1 = (yp == H2 - 1) ? H2 - 1 : yp + 1;
    const int xm1 = (m0 == 0)      ? 0      : m0 - 1;
    const int xp4 = (m0 + 4 > W2 - 1) ? W2 - 1 : m0 + 4;

    const int predoff = (yp << 11) + x0;   // (2*yp)*1024 + x0 within a batch
    const int offA = (ym1 << 9);
    const int offB = (yp  << 9);
    const int offC = (yp1 << 9);

    float img_local = 0.0f;
    #pragma unroll
    for (int i = 0; i < 4; ++i) {
        const int bb = b0 + 8 * i;
        const float* pr = pred + (bb << 20) + predoff;
        const float4 pe0 = ((const float4*)pr)[0];          // row 2yp
        const float4 pe1 = ((const float4*)pr)[1];
        const float4 po0 = ((const float4*)(pr + WDIM))[0]; // row 2yp+1
        const float4 po1 = ((const float4*)(pr + WDIM))[1];

        const float* tb = tgt + (bb << 18);
        const float* tA = tb + offA;
        const float* tB = tb + offB;
        const float* tC = tb + offC;

        const float4 a4 = *(const float4*)(tA + m0);
        const float4 b4 = *(const float4*)(tB + m0);
        const float4 c4 = *(const float4*)(tC + m0);
        const float la = tA[xm1], ra = tA[xp4];
        const float lb = tB[xm1], rb = tB[xp4];
        const float lc = tC[xm1], rc = tC[xp4];

        // vertical interp across the 6-column window [m0-1 .. m0+4]
        float e[6], o[6];
        e[0] = 0.25f * la   + 0.75f * lb;    o[0] = 0.75f * lb   + 0.25f * lc;
        e[1] = 0.25f * a4.x + 0.75f * b4.x;  o[1] = 0.75f * b4.x + 0.25f * c4.x;
        e[2] = 0.25f * a4.y + 0.75f * b4.y;  o[2] = 0.75f * b4.y + 0.25f * c4.y;
        e[3] = 0.25f * a4.z + 0.75f * b4.z;  o[3] = 0.75f * b4.z + 0.25f * c4.z;
        e[4] = 0.25f * a4.w + 0.75f * b4.w;  o[4] = 0.75f * b4.w + 0.25f * c4.w;
        e[5] = 0.25f * ra   + 0.75f * rb;    o[5] = 0.75f * rb   + 0.25f * rc;

        const float pev[8] = {pe0.x, pe0.y, pe0.z, pe0.w, pe1.x, pe1.y, pe1.z, pe1.w};
        const float pov[8] = {po0.x, po0.y, po0.z, po0.w, po1.x, po1.y, po1.z, po1.w};

        // horizontal interp (even,odd per m-col) + squared diff, 16 pixels
        #pragma unroll
        for (int k = 0; k < 4; ++k) {
            const float te0 = 0.25f * e[k]     + 0.75f * e[k + 1];
            const float te1 = 0.75f * e[k + 1] + 0.25f * e[k + 2];
            const float to0 = 0.25f * o[k]     + 0.75f * o[k + 1];
            const float to1 = 0.75f * o[k + 1] + 0.25f * o[k + 2];
            const float d0 = pev[2 * k]     - te0;
            const float d1 = pev[2 * k + 1] - te1;
            const float d2 = pov[2 * k]     - to0;
            const float d3 = pov[2 * k + 1] - to1;
            img_local += d0 * d0 + d1 * d1 + d2 * d2 + d3 * d3;
        }
    }

    const float bi = blockReduceSum(img_local, smem);
    if (threadIdx.x == 0) img_part[blockIdx.x] = bi;
}

// ---------------------------------------------------------------------------
// Kernel B: reduce 2048 img partials + 32 stn partials, write 3 outputs.
// ---------------------------------------------------------------------------
__global__ __launch_bounds__(256) void finalize_kernel(
        const float* __restrict__ img_part,
        const float* __restrict__ stn_part,
        float* __restrict__ out) {
    __shared__ float smem[4];

    float v = 0.0f;
    #pragma unroll
    for (int i = 0; i < NBLOCKS / 256; ++i)
        v += img_part[threadIdx.x + i * 256];
    const float img_sum = blockReduceSum(v, smem);
    __syncthreads();   // smem reuse

    float s = (threadIdx.x < 32) ? stn_part[threadIdx.x] : 0.0f;
    const float stn_sum = blockReduceSum(s, smem);

    if (threadIdx.x == 0) {
        const float img = img_sum * (1.0f / ((float)BATCH * HDIM * WDIM));
        const float stn = stn_sum * (1.0f / ((float)BATCH * NSTN));
        out[0] = img + 0.5f * stn;   // IMAGE_W=1.0, STATION_W=0.5
        out[1] = img;
        out[2] = stn;
    }
}

extern "C" void kernel_launch(void* const* d_in, const int* in_sizes, int n_in,
                              void* d_out, int out_size, void* d_ws, size_t ws_size,
                              hipStream_t stream) {
    const float* pred   = (const float*)d_in[0];
    const float* tgt    = (const float*)d_in[1];
    const int*   pos    = (const int*)d_in[2];
    const float* runoff = (const float*)d_in[3];
    float* out = (float*)d_out;
    float* img_part = (float*)d_ws;            // [NBLOCKS]
    float* stn_part = img_part + NBLOCKS;      // [32]

    // No memset needed: every partial slot is written unconditionally.
    fused_compute_kernel<<<NBLOCKS, 256, 0, stream>>>(pred, tgt, pos, runoff,
                                                      img_part, stn_part);
    finalize_kernel<<<1, 256, 0, stream>>>(img_part, stn_part, out);
}